// Round 3
// baseline (229.466 us; speedup 1.0000x reference)
//
#include <hip/hip_runtime.h>
#include <math.h>

#define KNBR 16
#define DIM 64
#define NREL 32
#define EPB 4   // batch elements per 512-thread block (2 waves each)

__global__ __launch_bounds__(512, 8) void kgnnls_kernel(
    const int* __restrict__ u_ids, const int* __restrict__ i_ids,
    const int* __restrict__ adj_entity, const int* __restrict__ adj_relation,
    const float* __restrict__ user_emb, const float* __restrict__ entity_emb,
    const float* __restrict__ relation_emb,
    const float* __restrict__ W0, const float* __restrict__ b0,
    const float* __restrict__ W1, const float* __restrict__ b1,
    float* __restrict__ out, int B)
{
    const int tid   = threadIdx.x;
    const int elem  = tid >> 7;         // 0..3: batch element slot
    const int sw    = (tid >> 6) & 1;   // sub-wave: owns k in [8*sw, 8*sw+8)
    const int lane  = tid & 63;         // dual role: dim d / output e
    const int wbase = sw * 8;
    int b = blockIdx.x * EPB + elem;
    if (b >= B) b = B - 1;              // duplicate work, benign duplicate write

    __shared__ float xbuf[EPB][17][DIM];
    __shared__ float uebuf[EPB][DIM];
    __shared__ float pbuf[EPB][2][DIM];  // cross-wave partials

    const int u  = u_ids[b];
    const int i0 = i_ids[b];

    const float ue = user_emb[u * DIM + lane];
    uebuf[elem][lane] = ue;
    const float bias0 = b0[lane];

    __syncthreads();  // uebuf ready

    // s[r] at lane r (r < 33): s = (1/64) * dot(ue, relation_emb[r])
    float s_val = 0.f;
    if (lane < NREL + 1) {
        const float4* rrow = (const float4*)(relation_emb + lane * DIM);
        const float4* ub   = (const float4*)uebuf[elem];
        float acc = 0.f;
        #pragma unroll
        for (int q = 0; q < 16; ++q) {
            float4 r4 = rrow[q];
            float4 u4 = ub[q];   // same-address -> LDS broadcast
            acc += r4.x*u4.x + r4.y*u4.y + r4.z*u4.z + r4.w*u4.w;
        }
        s_val = acc * (1.0f / DIM);
    }

    // hop-0 indices at lanes 0..15 (redundant in both sub-waves; 16 ints)
    int e1k = 0, r0k = 0;
    if (lane < KNBR) {
        e1k = adj_entity  [i0 * KNBR + lane];
        r0k = adj_relation[i0 * KNBR + lane];
    }

    // softmax over k (16) for hop-0 scores
    float sc0 = __shfl(s_val, r0k);
    float m0 = sc0;
    m0 = fmaxf(m0, __shfl_xor(m0, 1));
    m0 = fmaxf(m0, __shfl_xor(m0, 2));
    m0 = fmaxf(m0, __shfl_xor(m0, 4));
    m0 = fmaxf(m0, __shfl_xor(m0, 8));
    float ex0 = __expf(sc0 - m0);
    float z0 = ex0;
    z0 += __shfl_xor(z0, 1);
    z0 += __shfl_xor(z0, 2);
    z0 += __shfl_xor(z0, 4);
    z0 += __shfl_xor(z0, 8);
    const float attn0 = ex0 / z0;      // lanes 0..15 hold attn0[k]

    // hop-1 for this sub-wave: lane covers kloc = lane>>3 (0..7), 2 j's
    const int kloc = lane >> 3;
    const int jp   = (lane & 7) * 2;
    const int gk0  = wbase + kloc;
    const int ekn  = __shfl(e1k, gk0);
    const int2 e2i = *(const int2*)(adj_entity  + ekn * KNBR + jp);
    const int2 r2i = *(const int2*)(adj_relation + ekn * KNBR + jp);
    int e2idx[2] = { e2i.x, e2i.y };

    float sc1[2];
    sc1[0] = __shfl(s_val, r2i.x);
    sc1[1] = __shfl(s_val, r2i.y);

    // softmax over 16 j's: 8-lane groups (same kloc), 2 vals/lane
    float m1 = fmaxf(sc1[0], sc1[1]);
    m1 = fmaxf(m1, __shfl_xor(m1, 1));
    m1 = fmaxf(m1, __shfl_xor(m1, 2));
    m1 = fmaxf(m1, __shfl_xor(m1, 4));
    float a1[2];
    a1[0] = __expf(sc1[0] - m1);
    a1[1] = __expf(sc1[1] - m1);
    float z1 = a1[0] + a1[1];
    z1 += __shfl_xor(z1, 1);
    z1 += __shfl_xor(z1, 2);
    z1 += __shfl_xor(z1, 4);
    const float inv_z1 = 1.0f / z1;
    a1[0] *= inv_z1;
    a1[1] *= inv_z1;

    // Gather: 8 hop-1 rows + 128 hop-2 rows per sub-wave. Lane = d.
    float agg0p = 0.f;
    for (int kl = 0; kl < 8; ++kl) {
        const int gk = wbase + kl;
        const int ei = __shfl(e1k, gk);
        const float v1 = entity_emb[ei * DIM + lane];
        agg0p += __shfl(attn0, gk) * v1;

        float acc = 0.f;
        #pragma unroll
        for (int j = 0; j < 16; ++j) {
            const int src = kl * 8 + (j >> 1);
            const float a  = __shfl(a1[j & 1], src);
            const int  ei2 = __shfl(e2idx[j & 1], src);
            acc += a * entity_emb[ei2 * DIM + lane];
        }
        xbuf[elem][1 + gk][lane] = v1 + acc * (1.0f / KNBR);
    }
    pbuf[elem][sw][lane] = agg0p;

    __syncthreads();  // x rows 1..16 + agg0 partials ready

    if (sw == 0) {
        const float ev0 = entity_emb[i0 * DIM + lane];
        xbuf[elem][0][lane] = ev0 +
            (pbuf[elem][0][lane] + pbuf[elem][1][lane]) * (1.0f / KNBR);
        // own-wave write->read below is lgkmcnt-ordered; no barrier needed
    }

    // Layer-0: rows rbase..rbase+8 (sw0: 0..8, sw1: 8..16; row 8 duplicated)
    const int rbase = sw * 8;
    float hloc[9];
    #pragma unroll
    for (int r = 0; r < 9; ++r) hloc[r] = bias0;
    {
        const float4* wrow = (const float4*)(W0 + lane * DIM);
        #pragma unroll
        for (int q = 0; q < 16; ++q) {
            float4 w = wrow[q];  // L1-resident
            #pragma unroll
            for (int r = 0; r < 9; ++r) {
                float4 xv = ((const float4*)xbuf[elem][rbase + r])[q];
                hloc[r] += xv.x * w.x + xv.y * w.y + xv.z * w.z + xv.w * w.w;
            }
        }
    }
    #pragma unroll
    for (int r = 0; r < 9; ++r) hloc[r] = fmaxf(hloc[r], 0.f);

    __syncthreads();  // sw0's pbuf agg0 reads done; safe to reuse pbuf

    // aggL partial: this wave holds h rows rbase+1..rbase+8 = k in [wbase, wbase+8)
    float aggLp = 0.f;
    #pragma unroll
    for (int i = 1; i <= 8; ++i) {
        const float a0 = __shfl(attn0, wbase + i - 1);
        aggLp += a0 * hloc[i];
    }
    pbuf[elem][sw][lane] = aggLp;

    __syncthreads();  // aggL partials ready

    if (sw == 0) {
        const float xL = hloc[0] +
            (pbuf[elem][0][lane] + pbuf[elem][1][lane]) * (1.0f / KNBR);
        xbuf[elem][0][lane] = xL;  // own write->read, ordered

        float acc1 = b1[lane];
        const float4* wrow = (const float4*)(W1 + lane * DIM);
        const float4* xb   = (const float4*)xbuf[elem][0];
        #pragma unroll
        for (int q = 0; q < 16; ++q) {
            float4 w  = wrow[q];
            float4 xv = xb[q];
            acc1 += xv.x * w.x + xv.y * w.y + xv.z * w.z + xv.w * w.w;
        }
        const float item = tanhf(acc1);

        float p = ue * item;
        #pragma unroll
        for (int m = 1; m < 64; m <<= 1) p += __shfl_xor(p, m);
        if (lane == 0) out[b] = 1.0f / (1.0f + __expf(-p));
    }
}

extern "C" void kernel_launch(void* const* d_in, const int* in_sizes, int n_in,
                              void* d_out, int out_size, void* d_ws, size_t ws_size,
                              hipStream_t stream) {
    const int*   u_ids        = (const int*)  d_in[0];
    const int*   i_ids        = (const int*)  d_in[1];
    const int*   adj_entity   = (const int*)  d_in[2];
    const int*   adj_relation = (const int*)  d_in[3];
    const float* user_emb     = (const float*)d_in[4];
    const float* entity_emb   = (const float*)d_in[5];
    const float* relation_emb = (const float*)d_in[6];
    const float* W0           = (const float*)d_in[7];
    const float* b0           = (const float*)d_in[8];
    const float* W1           = (const float*)d_in[9];
    const float* b1           = (const float*)d_in[10];
    float* out = (float*)d_out;

    const int B = in_sizes[0];
    const int grid = (B + EPB - 1) / EPB;
    hipLaunchKernelGGL(kgnnls_kernel, dim3(grid), dim3(128 * EPB), 0, stream,
        u_ids, i_ids, adj_entity, adj_relation, user_emb, entity_emb,
        relation_emb, W0, b0, W1, b1, out, B);
}

// Round 4
// 204.037 us; speedup vs baseline: 1.1246x; 1.1246x over previous
//
#include <hip/hip_runtime.h>
#include <math.h>

#define KNBR 16
#define DIM 64
#define NREL 32
#define EPB 4   // batch elements per 512-thread block (2 waves each)

// launch_bounds(512, 6): 6 waves/EU -> 24 waves/CU cap, VGPR budget ~80.
// (512, 8) forced 32 VGPRs -> 231 MB of scratch spills (R3 post-mortem).
__global__ __launch_bounds__(512, 6) void kgnnls_kernel(
    const int* __restrict__ u_ids, const int* __restrict__ i_ids,
    const int* __restrict__ adj_entity, const int* __restrict__ adj_relation,
    const float* __restrict__ user_emb, const float* __restrict__ entity_emb,
    const float* __restrict__ relation_emb,
    const float* __restrict__ W0, const float* __restrict__ b0,
    const float* __restrict__ W1, const float* __restrict__ b1,
    float* __restrict__ out, int B)
{
    const int tid   = threadIdx.x;
    const int elem  = tid >> 7;         // 0..3: batch element slot
    const int sw    = (tid >> 6) & 1;   // sub-wave: owns k in [8*sw, 8*sw+8)
    const int lane  = tid & 63;         // dual role: dim d / output e
    const int wbase = sw * 8;
    int b = blockIdx.x * EPB + elem;
    if (b >= B) b = B - 1;              // duplicate work, benign duplicate write

    __shared__ float xbuf[EPB][17][DIM];
    __shared__ float uebuf[EPB][DIM];
    __shared__ float pbuf[EPB][2][DIM];  // cross-wave partials

    const int u  = u_ids[b];
    const int i0 = i_ids[b];

    const float ue = user_emb[u * DIM + lane];
    uebuf[elem][lane] = ue;
    const float bias0 = b0[lane];

    __syncthreads();  // uebuf ready

    // s[r] at lane r (r < 33): s = (1/64) * dot(ue, relation_emb[r])
    float s_val = 0.f;
    if (lane < NREL + 1) {
        const float4* rrow = (const float4*)(relation_emb + lane * DIM);
        const float4* ub   = (const float4*)uebuf[elem];
        float acc = 0.f;
        #pragma unroll
        for (int q = 0; q < 16; ++q) {
            float4 r4 = rrow[q];
            float4 u4 = ub[q];   // same-address -> LDS broadcast
            acc += r4.x*u4.x + r4.y*u4.y + r4.z*u4.z + r4.w*u4.w;
        }
        s_val = acc * (1.0f / DIM);
    }

    // hop-0 indices at lanes 0..15 (redundant in both sub-waves; 16 ints)
    int e1k = 0, r0k = 0;
    if (lane < KNBR) {
        e1k = adj_entity  [i0 * KNBR + lane];
        r0k = adj_relation[i0 * KNBR + lane];
    }

    // softmax over k (16) for hop-0 scores
    float sc0 = __shfl(s_val, r0k);
    float m0 = sc0;
    m0 = fmaxf(m0, __shfl_xor(m0, 1));
    m0 = fmaxf(m0, __shfl_xor(m0, 2));
    m0 = fmaxf(m0, __shfl_xor(m0, 4));
    m0 = fmaxf(m0, __shfl_xor(m0, 8));
    float ex0 = __expf(sc0 - m0);
    float z0 = ex0;
    z0 += __shfl_xor(z0, 1);
    z0 += __shfl_xor(z0, 2);
    z0 += __shfl_xor(z0, 4);
    z0 += __shfl_xor(z0, 8);
    const float attn0 = ex0 / z0;      // lanes 0..15 hold attn0[k]

    // hop-1 for this sub-wave: lane covers kloc = lane>>3 (0..7), 2 j's
    const int kloc = lane >> 3;
    const int jp   = (lane & 7) * 2;
    const int gk0  = wbase + kloc;
    const int ekn  = __shfl(e1k, gk0);
    const int2 e2i = *(const int2*)(adj_entity  + ekn * KNBR + jp);
    const int2 r2i = *(const int2*)(adj_relation + ekn * KNBR + jp);
    int e2idx[2] = { e2i.x, e2i.y };

    float sc1[2];
    sc1[0] = __shfl(s_val, r2i.x);
    sc1[1] = __shfl(s_val, r2i.y);

    // softmax over 16 j's: 8-lane groups (same kloc), 2 vals/lane
    float m1 = fmaxf(sc1[0], sc1[1]);
    m1 = fmaxf(m1, __shfl_xor(m1, 1));
    m1 = fmaxf(m1, __shfl_xor(m1, 2));
    m1 = fmaxf(m1, __shfl_xor(m1, 4));
    float a1[2];
    a1[0] = __expf(sc1[0] - m1);
    a1[1] = __expf(sc1[1] - m1);
    float z1 = a1[0] + a1[1];
    z1 += __shfl_xor(z1, 1);
    z1 += __shfl_xor(z1, 2);
    z1 += __shfl_xor(z1, 4);
    const float inv_z1 = 1.0f / z1;
    a1[0] *= inv_z1;
    a1[1] *= inv_z1;

    // Gather: 8 hop-1 rows + 128 hop-2 rows per sub-wave. Lane = d.
    float agg0p = 0.f;
    for (int kl = 0; kl < 8; ++kl) {
        const int gk = wbase + kl;
        const int ei = __shfl(e1k, gk);
        const float v1 = entity_emb[ei * DIM + lane];
        agg0p += __shfl(attn0, gk) * v1;

        float acc = 0.f;
        #pragma unroll
        for (int j = 0; j < 16; ++j) {
            const int src = kl * 8 + (j >> 1);
            const float a  = __shfl(a1[j & 1], src);
            const int  ei2 = __shfl(e2idx[j & 1], src);
            acc += a * entity_emb[ei2 * DIM + lane];
        }
        xbuf[elem][1 + gk][lane] = v1 + acc * (1.0f / KNBR);
    }
    pbuf[elem][sw][lane] = agg0p;

    __syncthreads();  // x rows 1..16 + agg0 partials ready

    if (sw == 0) {
        const float ev0 = entity_emb[i0 * DIM + lane];
        xbuf[elem][0][lane] = ev0 +
            (pbuf[elem][0][lane] + pbuf[elem][1][lane]) * (1.0f / KNBR);
        // own-wave write->read below is lgkmcnt-ordered; no barrier needed
    }

    // Layer-0: rows rbase..rbase+8 (sw0: 0..8, sw1: 8..16; row 8 duplicated)
    const int rbase = sw * 8;
    float hloc[9];
    #pragma unroll
    for (int r = 0; r < 9; ++r) hloc[r] = bias0;
    {
        const float4* wrow = (const float4*)(W0 + lane * DIM);
        #pragma unroll
        for (int q = 0; q < 16; ++q) {
            float4 w = wrow[q];  // L1-resident
            #pragma unroll
            for (int r = 0; r < 9; ++r) {
                float4 xv = ((const float4*)xbuf[elem][rbase + r])[q];
                hloc[r] += xv.x * w.x + xv.y * w.y + xv.z * w.z + xv.w * w.w;
            }
        }
    }
    #pragma unroll
    for (int r = 0; r < 9; ++r) hloc[r] = fmaxf(hloc[r], 0.f);

    __syncthreads();  // sw0's pbuf agg0 reads done; safe to reuse pbuf

    // aggL partial: this wave holds h rows rbase+1..rbase+8 = k in [wbase, wbase+8)
    float aggLp = 0.f;
    #pragma unroll
    for (int i = 1; i <= 8; ++i) {
        const float a0 = __shfl(attn0, wbase + i - 1);
        aggLp += a0 * hloc[i];
    }
    pbuf[elem][sw][lane] = aggLp;

    __syncthreads();  // aggL partials ready

    if (sw == 0) {
        const float xL = hloc[0] +
            (pbuf[elem][0][lane] + pbuf[elem][1][lane]) * (1.0f / KNBR);
        xbuf[elem][0][lane] = xL;  // own write->read, ordered

        float acc1 = b1[lane];
        const float4* wrow = (const float4*)(W1 + lane * DIM);
        const float4* xb   = (const float4*)xbuf[elem][0];
        #pragma unroll
        for (int q = 0; q < 16; ++q) {
            float4 w  = wrow[q];
            float4 xv = xb[q];
            acc1 += xv.x * w.x + xv.y * w.y + xv.z * w.z + xv.w * w.w;
        }
        const float item = tanhf(acc1);

        float p = ue * item;
        #pragma unroll
        for (int m = 1; m < 64; m <<= 1) p += __shfl_xor(p, m);
        if (lane == 0) out[b] = 1.0f / (1.0f + __expf(-p));
    }
}

extern "C" void kernel_launch(void* const* d_in, const int* in_sizes, int n_in,
                              void* d_out, int out_size, void* d_ws, size_t ws_size,
                              hipStream_t stream) {
    const int*   u_ids        = (const int*)  d_in[0];
    const int*   i_ids        = (const int*)  d_in[1];
    const int*   adj_entity   = (const int*)  d_in[2];
    const int*   adj_relation = (const int*)  d_in[3];
    const float* user_emb     = (const float*)d_in[4];
    const float* entity_emb   = (const float*)d_in[5];
    const float* relation_emb = (const float*)d_in[6];
    const float* W0           = (const float*)d_in[7];
    const float* b0           = (const float*)d_in[8];
    const float* W1           = (const float*)d_in[9];
    const float* b1           = (const float*)d_in[10];
    float* out = (float*)d_out;

    const int B = in_sizes[0];
    const int grid = (B + EPB - 1) / EPB;
    hipLaunchKernelGGL(kgnnls_kernel, dim3(grid), dim3(128 * EPB), 0, stream,
        u_ids, i_ids, adj_entity, adj_relation, user_emb, entity_emb,
        relation_emb, W0, b0, W1, b1, out, B);
}

// Round 5
// 190.797 us; speedup vs baseline: 1.2027x; 1.0694x over previous
//
#include <hip/hip_runtime.h>
#include <math.h>

#define KNBR 16
#define DIM 64
#define NREL 32
#define EPB 4   // batch elements per 512-thread block (2 waves each)

// Compiler VGPR budget model (fitted R2/R3/R4): budget = 256/waves_per_EU
// (the allocator uses a 256-reg pool, not HW's 512). (512,4) -> 64 VGPRs,
// which the HW still runs at 8 waves/EU = 32 waves/CU. (512,6/8) -> 40/32
// VGPRs and 173/231 MB of scratch spill traffic.
__global__ __launch_bounds__(512, 4) void kgnnls_kernel(
    const int* __restrict__ u_ids, const int* __restrict__ i_ids,
    const int* __restrict__ adj_entity, const int* __restrict__ adj_relation,
    const float* __restrict__ user_emb, const float* __restrict__ entity_emb,
    const float* __restrict__ relation_emb,
    const float* __restrict__ W0, const float* __restrict__ b0,
    const float* __restrict__ W1, const float* __restrict__ b1,
    float* __restrict__ out, int B)
{
    const int tid   = threadIdx.x;
    const int elem  = tid >> 7;         // 0..3: batch element slot
    const int sw    = (tid >> 6) & 1;   // sub-wave: owns k in [8*sw, 8*sw+8)
    const int lane  = tid & 63;         // dual role: dim d / output e
    const int wbase = sw * 8;
    int b = blockIdx.x * EPB + elem;
    if (b >= B) b = B - 1;              // duplicate work, benign duplicate write

    __shared__ float xbuf[EPB][17][DIM];
    __shared__ float uebuf[EPB][DIM];
    __shared__ float pbuf[EPB][2][DIM];  // cross-wave partials

    const int u  = u_ids[b];
    const int i0 = i_ids[b];

    const float ue = user_emb[u * DIM + lane];
    uebuf[elem][lane] = ue;
    const float bias0 = b0[lane];

    __syncthreads();  // uebuf ready

    // s[r] at lane r (r < 33): s = (1/64) * dot(ue, relation_emb[r])
    float s_val = 0.f;
    if (lane < NREL + 1) {
        const float4* rrow = (const float4*)(relation_emb + lane * DIM);
        const float4* ub   = (const float4*)uebuf[elem];
        float acc = 0.f;
        #pragma unroll
        for (int q = 0; q < 16; ++q) {
            float4 r4 = rrow[q];
            float4 u4 = ub[q];   // same-address -> LDS broadcast
            acc += r4.x*u4.x + r4.y*u4.y + r4.z*u4.z + r4.w*u4.w;
        }
        s_val = acc * (1.0f / DIM);
    }

    // hop-0 indices at lanes 0..15 (redundant in both sub-waves; 16 ints)
    int e1k = 0, r0k = 0;
    if (lane < KNBR) {
        e1k = adj_entity  [i0 * KNBR + lane];
        r0k = adj_relation[i0 * KNBR + lane];
    }

    // softmax over k (16) for hop-0 scores
    float sc0 = __shfl(s_val, r0k);
    float m0 = sc0;
    m0 = fmaxf(m0, __shfl_xor(m0, 1));
    m0 = fmaxf(m0, __shfl_xor(m0, 2));
    m0 = fmaxf(m0, __shfl_xor(m0, 4));
    m0 = fmaxf(m0, __shfl_xor(m0, 8));
    float ex0 = __expf(sc0 - m0);
    float z0 = ex0;
    z0 += __shfl_xor(z0, 1);
    z0 += __shfl_xor(z0, 2);
    z0 += __shfl_xor(z0, 4);
    z0 += __shfl_xor(z0, 8);
    const float attn0 = ex0 / z0;      // lanes 0..15 hold attn0[k]

    // hop-1 for this sub-wave: lane covers kloc = lane>>3 (0..7), 2 j's
    const int kloc = lane >> 3;
    const int jp   = (lane & 7) * 2;
    const int gk0  = wbase + kloc;
    const int ekn  = __shfl(e1k, gk0);
    const int2 e2i = *(const int2*)(adj_entity  + ekn * KNBR + jp);
    const int2 r2i = *(const int2*)(adj_relation + ekn * KNBR + jp);
    int e2idx[2] = { e2i.x, e2i.y };

    float sc1[2];
    sc1[0] = __shfl(s_val, r2i.x);
    sc1[1] = __shfl(s_val, r2i.y);

    // softmax over 16 j's: 8-lane groups (same kloc), 2 vals/lane
    float m1 = fmaxf(sc1[0], sc1[1]);
    m1 = fmaxf(m1, __shfl_xor(m1, 1));
    m1 = fmaxf(m1, __shfl_xor(m1, 2));
    m1 = fmaxf(m1, __shfl_xor(m1, 4));
    float a1[2];
    a1[0] = __expf(sc1[0] - m1);
    a1[1] = __expf(sc1[1] - m1);
    float z1 = a1[0] + a1[1];
    z1 += __shfl_xor(z1, 1);
    z1 += __shfl_xor(z1, 2);
    z1 += __shfl_xor(z1, 4);
    const float inv_z1 = 1.0f / z1;
    a1[0] *= inv_z1;
    a1[1] *= inv_z1;

    // Gather: 8 hop-1 rows + 128 hop-2 rows per sub-wave. Lane = d.
    float agg0p = 0.f;
    for (int kl = 0; kl < 8; ++kl) {
        const int gk = wbase + kl;
        const int ei = __shfl(e1k, gk);
        const float v1 = entity_emb[ei * DIM + lane];
        agg0p += __shfl(attn0, gk) * v1;

        float acc = 0.f;
        #pragma unroll
        for (int j = 0; j < 16; ++j) {
            const int src = kl * 8 + (j >> 1);
            const float a  = __shfl(a1[j & 1], src);
            const int  ei2 = __shfl(e2idx[j & 1], src);
            acc += a * entity_emb[ei2 * DIM + lane];
        }
        xbuf[elem][1 + gk][lane] = v1 + acc * (1.0f / KNBR);
    }
    pbuf[elem][sw][lane] = agg0p;

    __syncthreads();  // x rows 1..16 + agg0 partials ready

    if (sw == 0) {
        const float ev0 = entity_emb[i0 * DIM + lane];
        xbuf[elem][0][lane] = ev0 +
            (pbuf[elem][0][lane] + pbuf[elem][1][lane]) * (1.0f / KNBR);
        // own-wave write->read below is lgkmcnt-ordered; no barrier needed
    }

    // Layer-0: rows rbase..rbase+8 (sw0: 0..8, sw1: 8..16; row 8 duplicated)
    const int rbase = sw * 8;
    float hloc[9];
    #pragma unroll
    for (int r = 0; r < 9; ++r) hloc[r] = bias0;
    {
        const float4* wrow = (const float4*)(W0 + lane * DIM);
        #pragma unroll
        for (int q = 0; q < 16; ++q) {
            float4 w = wrow[q];  // L1-resident
            #pragma unroll
            for (int r = 0; r < 9; ++r) {
                float4 xv = ((const float4*)xbuf[elem][rbase + r])[q];
                hloc[r] += xv.x * w.x + xv.y * w.y + xv.z * w.z + xv.w * w.w;
            }
        }
    }
    #pragma unroll
    for (int r = 0; r < 9; ++r) hloc[r] = fmaxf(hloc[r], 0.f);

    __syncthreads();  // sw0's pbuf agg0 reads done; safe to reuse pbuf

    // aggL partial: this wave holds h rows rbase+1..rbase+8 = k in [wbase, wbase+8)
    float aggLp = 0.f;
    #pragma unroll
    for (int i = 1; i <= 8; ++i) {
        const float a0 = __shfl(attn0, wbase + i - 1);
        aggLp += a0 * hloc[i];
    }
    pbuf[elem][sw][lane] = aggLp;

    __syncthreads();  // aggL partials ready

    if (sw == 0) {
        const float xL = hloc[0] +
            (pbuf[elem][0][lane] + pbuf[elem][1][lane]) * (1.0f / KNBR);
        xbuf[elem][0][lane] = xL;  // own write->read, ordered

        float acc1 = b1[lane];
        const float4* wrow = (const float4*)(W1 + lane * DIM);
        const float4* xb   = (const float4*)xbuf[elem][0];
        #pragma unroll
        for (int q = 0; q < 16; ++q) {
            float4 w  = wrow[q];
            float4 xv = xb[q];
            acc1 += xv.x * w.x + xv.y * w.y + xv.z * w.z + xv.w * w.w;
        }
        const float item = tanhf(acc1);

        float p = ue * item;
        #pragma unroll
        for (int m = 1; m < 64; m <<= 1) p += __shfl_xor(p, m);
        if (lane == 0) out[b] = 1.0f / (1.0f + __expf(-p));
    }
}

extern "C" void kernel_launch(void* const* d_in, const int* in_sizes, int n_in,
                              void* d_out, int out_size, void* d_ws, size_t ws_size,
                              hipStream_t stream) {
    const int*   u_ids        = (const int*)  d_in[0];
    const int*   i_ids        = (const int*)  d_in[1];
    const int*   adj_entity   = (const int*)  d_in[2];
    const int*   adj_relation = (const int*)  d_in[3];
    const float* user_emb     = (const float*)d_in[4];
    const float* entity_emb   = (const float*)d_in[5];
    const float* relation_emb = (const float*)d_in[6];
    const float* W0           = (const float*)d_in[7];
    const float* b0           = (const float*)d_in[8];
    const float* W1           = (const float*)d_in[9];
    const float* b1           = (const float*)d_in[10];
    float* out = (float*)d_out;

    const int B = in_sizes[0];
    const int grid = (B + EPB - 1) / EPB;
    hipLaunchKernelGGL(kgnnls_kernel, dim3(grid), dim3(128 * EPB), 0, stream,
        u_ids, i_ids, adj_entity, adj_relation, user_emb, entity_emb,
        relation_emb, W0, b0, W1, b1, out, B);
}

// Round 6
// 158.202 us; speedup vs baseline: 1.4505x; 1.2060x over previous
//
#include <hip/hip_runtime.h>
#include <math.h>

#define KNBR 16
#define DIM 64
#define NREL 32
#define WPB 4   // batch elements (one wave each) per 256-thread block

// launch_bounds(256,2): compiler VGPR budget = 256/2 = 128 (fitted model
// R2..R5: budget = 256/waves_per_EU). Grid is 4096 waves total = 16/CU cap,
// and HW allows 16 waves/CU for VGPR in [64,128) (m69 cliff) -> a 128-reg
// budget costs zero achievable occupancy here. Spend the regs on MLP:
// 17 preloaded hop-1 rows + 16-wide batched hop-2 gathers per k.
__global__ __launch_bounds__(256, 2) void kgnnls_kernel(
    const int* __restrict__ u_ids, const int* __restrict__ i_ids,
    const int* __restrict__ adj_entity, const int* __restrict__ adj_relation,
    const float* __restrict__ user_emb, const float* __restrict__ entity_emb,
    const float* __restrict__ relation_emb,
    const float* __restrict__ W0, const float* __restrict__ b0,
    const float* __restrict__ W1, const float* __restrict__ b1,
    float* __restrict__ out, int B)
{
    const int tid  = threadIdx.x;
    const int wave = tid >> 6;
    const int lane = tid & 63;          // dual role: dim index d / output index e
    int b = blockIdx.x * WPB + wave;
    if (b >= B) b = B - 1;              // duplicate work, benign duplicate write

    __shared__ float xbuf[WPB][17][DIM];
    __shared__ float uebuf[WPB][DIM];

    const int u  = u_ids[b];
    const int i0 = i_ids[b];

    const float ue = user_emb[u * DIM + lane];
    uebuf[wave][lane] = ue;
    const float bias0 = b0[lane];

    __syncthreads();

    // s[r] at lane r (r < 33): s = (1/64) * dot(ue, relation_emb[r])
    float s_val = 0.f;
    if (lane < NREL + 1) {
        const float4* rrow = (const float4*)(relation_emb + lane * DIM);
        const float4* ub   = (const float4*)uebuf[wave];
        float acc = 0.f;
        #pragma unroll
        for (int q = 0; q < 16; ++q) {
            float4 r4 = rrow[q];
            float4 u4 = ub[q];   // same address across lanes -> LDS broadcast
            acc += r4.x*u4.x + r4.y*u4.y + r4.z*u4.z + r4.w*u4.w;
        }
        s_val = acc * (1.0f / DIM);
    }

    // hop-0 neighbor/relation indices at lanes 0..15
    int e1k = 0, r0k = 0;
    if (lane < KNBR) {
        e1k = adj_entity  [i0 * KNBR + lane];
        r0k = adj_relation[i0 * KNBR + lane];
    }

    // softmax over k (16) for hop-0 scores, valid at lanes 0..15
    float sc0 = __shfl(s_val, r0k);
    float m0 = sc0;
    m0 = fmaxf(m0, __shfl_xor(m0, 1));
    m0 = fmaxf(m0, __shfl_xor(m0, 2));
    m0 = fmaxf(m0, __shfl_xor(m0, 4));
    m0 = fmaxf(m0, __shfl_xor(m0, 8));
    float ex0 = __expf(sc0 - m0);
    float z0 = ex0;
    z0 += __shfl_xor(z0, 1);
    z0 += __shfl_xor(z0, 2);
    z0 += __shfl_xor(z0, 4);
    z0 += __shfl_xor(z0, 8);
    const float attn0 = ex0 / z0;     // lanes 0..15 hold attn0[k]

    // hop-1: lane handles k = lane>>2, j in [4*(lane&3), +4)
    const int kk = lane >> 2;
    const int jb = (lane & 3) * 4;
    const int ek = __shfl(e1k, kk);
    const int4 e2i = *(const int4*)(adj_entity  + ek * KNBR + jb);
    const int4 r2i = *(const int4*)(adj_relation + ek * KNBR + jb);
    int e2idx[4] = { e2i.x, e2i.y, e2i.z, e2i.w };

    float sc1[4];
    sc1[0] = __shfl(s_val, r2i.x);
    sc1[1] = __shfl(s_val, r2i.y);
    sc1[2] = __shfl(s_val, r2i.z);
    sc1[3] = __shfl(s_val, r2i.w);

    // softmax over the 16 j's: intra-lane over 4 + xor over lanes {1,2}
    float m1 = fmaxf(fmaxf(sc1[0], sc1[1]), fmaxf(sc1[2], sc1[3]));
    m1 = fmaxf(m1, __shfl_xor(m1, 1));
    m1 = fmaxf(m1, __shfl_xor(m1, 2));
    float a1[4];
    float z1 = 0.f;
    #pragma unroll
    for (int t = 0; t < 4; ++t) { a1[t] = __expf(sc1[t] - m1); z1 += a1[t]; }
    z1 += __shfl_xor(z1, 1);
    z1 += __shfl_xor(z1, 2);
    const float inv_z1 = 1.0f / z1;
    #pragma unroll
    for (int t = 0; t < 4; ++t) a1[t] *= inv_z1;

    // ---- Gather phase, MLP-maximized ----
    // Preload all 17 "self" rows (16 hop-1 + item row): 17 loads in flight.
    float v1a[KNBR];
    #pragma unroll
    for (int k = 0; k < KNBR; ++k) {
        const int ei = __shfl(e1k, k);
        v1a[k] = entity_emb[ei * DIM + lane];
    }
    const float ev0 = entity_emb[i0 * DIM + lane];

    float agg0 = 0.f;
    for (int k = 0; k < KNBR; ++k) {
        // Batch all 16 hop-2 gathers for this k before consuming any.
        float v2[16];
        #pragma unroll
        for (int j = 0; j < 16; ++j) {
            const int src = 4 * k + (j >> 2);           // lane holding (k, j)
            const int ei2 = __shfl(e2idx[j & 3], src);
            v2[j] = entity_emb[ei2 * DIM + lane];
        }
        float acc = 0.f;
        #pragma unroll
        for (int j = 0; j < 16; ++j) {
            const int src = 4 * k + (j >> 2);
            acc += __shfl(a1[j & 3], src) * v2[j];
        }
        agg0 += __shfl(attn0, k) * v1a[k];
        xbuf[wave][1 + k][lane] = v1a[k] + acc * (1.0f / KNBR);
    }
    xbuf[wave][0][lane] = ev0 + agg0 * (1.0f / KNBR);
    __syncthreads();

    // Layer-0 matmul: h[r][e] = relu( sum_d x[r][d] * W0[e][d] + b0[e] ), 17 rows
    float h[17];
    {
        #pragma unroll
        for (int r = 0; r < 17; ++r) h[r] = bias0;
        const float4* wrow = (const float4*)(W0 + lane * DIM);
        #pragma unroll
        for (int q = 0; q < 16; ++q) {
            float4 w = wrow[q];   // L1-resident
            #pragma unroll
            for (int r = 0; r < 17; ++r) {
                float4 xv = ((const float4*)xbuf[wave][r])[q];  // broadcast read
                h[r] += xv.x * w.x + xv.y * w.y + xv.z * w.z + xv.w * w.w;
            }
        }
        #pragma unroll
        for (int r = 0; r < 17; ++r) h[r] = fmaxf(h[r], 0.f);
    }

    // Layer-1: agg over h1 with the SAME attn0, then tanh((h0+agg) @ W1^T + b1)
    float aggL = 0.f;
    #pragma unroll
    for (int k = 0; k < KNBR; ++k) {
        const float a0 = __shfl(attn0, k);
        aggL += a0 * h[1 + k];
    }
    const float xL = h[0] + aggL * (1.0f / KNBR);
    __syncthreads();
    xbuf[wave][0][lane] = xL;
    __syncthreads();

    float acc1 = b1[lane];
    {
        const float4* wrow = (const float4*)(W1 + lane * DIM);
        const float4* xb   = (const float4*)xbuf[wave][0];
        #pragma unroll
        for (int q = 0; q < 16; ++q) {
            float4 w  = wrow[q];
            float4 xv = xb[q];
            acc1 += xv.x * w.x + xv.y * w.y + xv.z * w.z + xv.w * w.w;
        }
    }
    const float item = tanhf(acc1);

    // score = sigmoid( sum_d ue[d] * item[d] )
    float p = ue * item;
    #pragma unroll
    for (int m = 1; m < 64; m <<= 1) p += __shfl_xor(p, m);
    if (lane == 0) out[b] = 1.0f / (1.0f + __expf(-p));
}

extern "C" void kernel_launch(void* const* d_in, const int* in_sizes, int n_in,
                              void* d_out, int out_size, void* d_ws, size_t ws_size,
                              hipStream_t stream) {
    const int*   u_ids        = (const int*)  d_in[0];
    const int*   i_ids        = (const int*)  d_in[1];
    const int*   adj_entity   = (const int*)  d_in[2];
    const int*   adj_relation = (const int*)  d_in[3];
    const float* user_emb     = (const float*)d_in[4];
    const float* entity_emb   = (const float*)d_in[5];
    const float* relation_emb = (const float*)d_in[6];
    const float* W0           = (const float*)d_in[7];
    const float* b0           = (const float*)d_in[8];
    const float* W1           = (const float*)d_in[9];
    const float* b1           = (const float*)d_in[10];
    float* out = (float*)d_out;

    const int B = in_sizes[0];
    const int grid = (B + WPB - 1) / WPB;
    hipLaunchKernelGGL(kgnnls_kernel, dim3(grid), dim3(64 * WPB), 0, stream,
        u_ids, i_ids, adj_entity, adj_relation, user_emb, entity_emb,
        relation_emb, W0, b0, W1, b1, out, B);
}